// Round 8
// baseline (889.297 us; speedup 1.0000x reference)
//
#include <hip/hip_runtime.h>
#include <hip/hip_bf16.h>

// ---------------- constants ----------------
#define TT 128
#define BB 64
#define NITEM (TT*BB*SEE)
#define SEE 10
typedef __attribute__((ext_vector_type(8))) short short8;    // 8 bf16
typedef __attribute__((ext_vector_type(4))) float floatx4;   // MFMA acc

static __device__ __forceinline__ float wave_sum(float v) {
  v += __shfl_xor(v, 32); v += __shfl_xor(v, 16); v += __shfl_xor(v, 8);
  v += __shfl_xor(v, 4);  v += __shfl_xor(v, 2);  v += __shfl_xor(v, 1);
  return v;
}
static __device__ __forceinline__ float wave_max(float v) {
  v = fmaxf(v, __shfl_xor(v, 32)); v = fmaxf(v, __shfl_xor(v, 16)); v = fmaxf(v, __shfl_xor(v, 8));
  v = fmaxf(v, __shfl_xor(v, 4));  v = fmaxf(v, __shfl_xor(v, 2));  v = fmaxf(v, __shfl_xor(v, 1));
  return v;
}
static __device__ __forceinline__ unsigned short f2bf(float x) {
  __hip_bfloat16 h = __float2bfloat16(x);
  return *reinterpret_cast<unsigned short*>(&h);
}
static __device__ __forceinline__ float bf2f(unsigned short u) {
  unsigned v = ((unsigned)u) << 16;
  return __builtin_bit_cast(float, v);
}
static __device__ __forceinline__ unsigned int pack2(float lo, float hi) {
  return (unsigned int)f2bf(lo) | ((unsigned int)f2bf(hi) << 16);
}
// LDS-only barrier: does not drain outstanding global loads (vmcnt).
static __device__ __forceinline__ void ldsbar() {
  asm volatile("s_waitcnt lgkmcnt(0)" ::: "memory");
  __builtin_amdgcn_s_barrier();
  asm volatile("" ::: "memory");
}

// ---------------- build V (and V^T per b) ----------------
__global__ void build_v(const int* __restrict__ prob_id, const int* __restrict__ skills,
                        const float* __restrict__ concept_emb, const float* __restrict__ prob_emb,
                        float* __restrict__ V, float* __restrict__ VT) {
  int tb = blockIdx.x; int t = tb >> 6, b = tb & 63; int d = threadIdx.x;
  int pid = prob_id[tb];
  float pr = pid ? prob_emb[(pid - 1) * 64 + d] : 0.0f;
  int cnt = 0; float sum = 0.0f;
#pragma unroll
  for (int c = 0; c < 4; ++c) {
    int sk = skills[tb * 4 + c];
    if (sk) { ++cnt; sum += concept_emb[(sk - 1) * 64 + d]; }
  }
  float mean = sum / (float)(cnt ? cnt : 1);
  V[tb * 128 + d] = mean;
  V[tb * 128 + 64 + d] = pr;
  VT[b * 16384 + d * 128 + t] = mean;
  VT[b * 16384 + (64 + d) * 128 + t] = pr;
}

// ---------------- massively parallel bf16 gather: AHV[item][192] ----------------
__global__ __launch_bounds__(256) void gather_ahv(
    const int* __restrict__ bg_index, const int* __restrict__ mem_prob_ids,
    const int* __restrict__ mem_concepts, const float* __restrict__ states_mem,
    const float* __restrict__ concept_emb, const float* __restrict__ prob_emb,
    unsigned short* __restrict__ AHV) {
  int gid = blockIdx.x * 256 + threadIdx.x;      // NITEM*96 threads
  int item = gid / 96, c2 = gid - 96 * item; int d = 2 * c2;
  int t = item / 640; int rem = item - t * 640; int b = rem / 10; int s = rem - b * 10;
  int g = bg_index[(t * 64 + b) * 20 + s];
  float v0, v1;
  if (d < 64) {
    float2 sv = *(const float2*)&states_mem[g * 64 + d];
    v0 = sv.x; v1 = sv.y;
  } else if (d < 128) {
    int dd = d - 64; float s0 = 0.f, s1 = 0.f; int cnt = 0;
#pragma unroll
    for (int c = 0; c < 4; ++c) {
      int sk = mem_concepts[g * 4 + c];
      if (sk) { ++cnt; float2 e = *(const float2*)&concept_emb[(sk - 1) * 64 + dd]; s0 += e.x; s1 += e.y; }
    }
    float inv = 1.0f / (float)(cnt ? cnt : 1);
    v0 = s0 * inv; v1 = s1 * inv;
  } else {
    int dd = d - 128; int pid = mem_prob_ids[g];
    if (pid) { float2 pv = *(const float2*)&prob_emb[(pid - 1) * 64 + dd]; v0 = pv.x; v1 = pv.y; }
    else { v0 = 0.f; v1 = 0.f; }
  }
  *(unsigned int*)&AHV[(size_t)item * 192 + d] = pack2(v0, v1);
}

// ---------------- generic fp32 GEMM ----------------
__global__ __launch_bounds__(256) void gemm_f32(
    const float* __restrict__ A, const float* __restrict__ B, float* __restrict__ C,
    const float* __restrict__ bias, int M, int N, int K,
    int lda, int ldb, int ldc, long sA, long sB, long sC, float scale) {
  __shared__ __align__(16) float As[64 * 36];
  __shared__ __align__(16) float Bs[32 * 64];
  const float* Ab = A + (long)blockIdx.z * sA;
  const float* Bb = B + (long)blockIdx.z * sB;
  float* Cb = C + (long)blockIdx.z * sC;
  int m0 = blockIdx.y * 64, n0 = blockIdx.x * 64;
  int tid = threadIdx.x;
  int ti = tid & 15, tj = tid >> 4;
  float acc[4][4] = {};
  for (int kc = 0; kc < K; kc += 32) {
#pragma unroll
    for (int p = 0; p < 2; ++p) {
      int q = tid + 256 * p;
      int row = q >> 3, kq = q & 7;
      *(float4*)&As[row * 36 + 4 * kq] = *(const float4*)&Ab[(size_t)(m0 + row) * lda + kc + 4 * kq];
    }
#pragma unroll
    for (int p = 0; p < 2; ++p) {
      int q = tid + 256 * p;
      int k = q >> 4, nq = q & 15;
      *(float4*)&Bs[k * 64 + 4 * nq] = *(const float4*)&Bb[(size_t)(kc + k) * ldb + n0 + 4 * nq];
    }
    __syncthreads();
#pragma unroll
    for (int k4 = 0; k4 < 8; ++k4) {
      float4 av[4], bv[4];
#pragma unroll
      for (int m = 0; m < 4; ++m) av[m] = *(const float4*)&As[(ti + 16 * m) * 36 + 4 * k4];
#pragma unroll
      for (int kk = 0; kk < 4; ++kk) bv[kk] = *(const float4*)&Bs[(4 * k4 + kk) * 64 + 4 * tj];
#pragma unroll
      for (int m = 0; m < 4; ++m) {
        const float* ap = (const float*)&av[m];
#pragma unroll
        for (int kk = 0; kk < 4; ++kk) {
          float a = ap[kk];
          acc[m][0] += a * bv[kk].x; acc[m][1] += a * bv[kk].y;
          acc[m][2] += a * bv[kk].z; acc[m][3] += a * bv[kk].w;
        }
      }
    }
    __syncthreads();
  }
  float4 bq = make_float4(0.f, 0.f, 0.f, 0.f);
  if (bias) bq = *(const float4*)&bias[n0 + 4 * tj];
#pragma unroll
  for (int m = 0; m < 4; ++m) {
    int row = m0 + ti + 16 * m;
    float4 o;
    o.x = acc[m][0] * scale + bq.x; o.y = acc[m][1] * scale + bq.y;
    o.z = acc[m][2] * scale + bq.z; o.w = acc[m][3] * scale + bq.w;
    *(float4*)&Cb[(size_t)row * ldc + n0 + 4 * tj] = o;
  }
}

// ---------------- small weight folds (needs M12) ----------------
__global__ __launch_bounds__(256) void k_small(
    const float* __restrict__ W_batch, const float* __restrict__ W_bg, const float* __restrict__ b_bg,
    const float* __restrict__ W_bgint, const float* __restrict__ b_bgint,
    const float* __restrict__ W_hisint, const float* __restrict__ b_hisint,
    const float* __restrict__ W_ih, const float* __restrict__ b_ih, const float* __restrict__ b_inmap,
    const float* __restrict__ W_pred, const float* __restrict__ b_pred, const float* __restrict__ dir_w,
    const float* __restrict__ b_batch,
    const float* __restrict__ M12, unsigned short* __restrict__ B1T, float* __restrict__ Hmix,
    float* __restrict__ WgT, float* __restrict__ BQG, float* __restrict__ biasQG,
    float* __restrict__ c4, float* __restrict__ cgx, float* __restrict__ uh,
    float* __restrict__ bgp, float* __restrict__ c0, float* __restrict__ dwv) {
  int idx = blockIdx.x * 256 + threadIdx.x;
  const int R0 = 49152, R1 = 86016, R2 = 122880, R3 = 147456, R4 = 196608,
            R5 = 229376, R6 = 278528, R7 = 278784, R8 = 278976, R9 = 279104,
            R10 = 279488, R11 = 279489, R12 = 279491, R13 = 280131;
  if (idx < R0) {
    int k = idx >> 8, n = idx & 255; int h = n >> 6, i = n & 63;
    float s = 0.f;
    for (int d = 0; d < 64; ++d) s += W_bg[h * 12288 + k * 64 + d] * W_batch[h * 12288 + i * 64 + d];
    B1T[n * 192 + k] = f2bf(s);
  } else if (idx < R1) {
    int r = idx - R0; int k = r / 192, c = r - k * 192;
    float s = 0.f;
    for (int j = 0; j < 384; ++j) s += W_bgint[k * 384 + j] * M12[j * 192 + c];
    B1T[(256 + c) * 192 + k] = f2bf(s);
  } else if (idx < R2) {
    int r = idx - R1; int k = r / 192, c = r - k * 192;
    float s = 0.f;
    for (int j = 0; j < 384; ++j) s += W_bgint[(192 + k) * 384 + j] * M12[j * 192 + c];
    B1T[(448 + c) * 192 + k] = f2bf(s);
  } else if (idx < R3) {
    int r = idx - R2; int i = r / 192, c = r - i * 192;
    float s = 0.f;
    for (int j = 0; j < 384; ++j) s += W_hisint[i * 384 + j] * M12[j * 192 + c];
    Hmix[i * 192 + c] = s;
  } else if (idx < R4) {
    int r = idx - R3; int h = r / 12288; int rem = r - h * 12288; int d = rem / 192, k = rem - d * 192;
    WgT[r] = W_bg[h * 12288 + k * 64 + d];
  } else if (idx < R5) {
    int r = idx - R4; int i = r >> 8, n = r & 255; int h = n >> 6, d = n & 63;
    BQG[i * 640 + n] = W_batch[h * 12288 + (64 + i) * 64 + d];
  } else if (idx < R6) {
    int r = idx - R5; int i = r / 384, c = r - i * 384;
    BQG[i * 640 + 256 + c] = (c < 192) ? M12[(384 + i) * 192 + c] : M12[(512 + i) * 192 + (c - 192)];
  } else if (idx < R7) {
    int n = idx - R6; int h = n >> 6, i = n & 63;
    float s = 0.f;
    for (int d = 0; d < 64; ++d) s += W_batch[h * 12288 + i * 64 + d] * b_bg[h * 64 + d];
    c4[n] = s;
  } else if (idx < R8) {
    int c = idx - R7;
    float e0 = __expf(dir_w[0]), e1 = __expf(dir_w[1]);
    float dw0 = e0 / (e0 + e1), dw1 = e1 / (e0 + e1);
    float s = b_ih[c];
    for (int i = 0; i < 256; ++i) s += b_inmap[i] * W_ih[i * 192 + c];
    for (int k = 0; k < 384; ++k) s += (dw0 * b_bgint[k] + dw1 * b_hisint[k]) * M12[k * 192 + c];
    cgx[c] = s;
  } else if (idx < R9) {
    int i = idx - R8;
    float s = 0.f;
    for (int j = 0; j < 384; ++j) s += W_hisint[i * 384 + j] * W_pred[j];
    uh[i] = s;
  } else if (idx < R10) {
    int k = idx - R9;
    float s = 0.f;
    for (int j = 0; j < 384; ++j) s += W_bgint[k * 384 + j] * W_pred[j];
    bgp[k] = s;
  } else if (idx < R11) {
    float e0 = __expf(dir_w[0]), e1 = __expf(dir_w[1]);
    float dw0 = e0 / (e0 + e1), dw1 = e1 / (e0 + e1);
    float s = b_pred[0];
    for (int k = 0; k < 384; ++k) s += (dw0 * b_bgint[k] + dw1 * b_hisint[k]) * W_pred[k];
    c0[0] = s;
  } else if (idx < R12) {
    float e0 = __expf(dir_w[0]), e1 = __expf(dir_w[1]);
    dwv[idx - R11] = (idx == R11) ? e0 / (e0 + e1) : e1 / (e0 + e1);
  } else if (idx < R13) {
    int i = idx - R12;
    biasQG[i] = (i < 256) ? b_batch[i] : 0.f;
  }
}

// ---------------- big GEMM via bf16 MFMA, split over col-tiles ----------------
#define APAD 200
#define BPAD 40
__global__ __launch_bounds__(256) void big_gemm(
    const int* __restrict__ bg_index, const int* __restrict__ mem_resp,
    const unsigned short* __restrict__ AHV, const unsigned short* __restrict__ B1T,
    const float* __restrict__ c4, unsigned short* __restrict__ P4s16, float* __restrict__ Cg) {
  __shared__ unsigned short As[128 * APAD];
  __shared__ unsigned short Bs[128 * BPAD];
  __shared__ int rf_l[128];
  int mt = blockIdx.x;
  int nt = blockIdx.y;     // one 128-col tile per block (5 total)
  int n0 = nt * 128;
  int tid = threadIdx.x;
  int lane = tid & 63, wv = tid >> 6;
  if (tid < 128) {
    int item = mt * 128 + tid;
    int t = item / 640; int rem = item - t * 640; int b = rem / 10; int s = rem - b * 10;
    int g = bg_index[(t * 64 + b) * 20 + s];
    rf_l[tid] = mem_resp[g];
  }
  for (int i = tid; i < 128 * 24; i += 256) {
    int row = i / 24, c = i - 24 * row;
    *(float4*)&As[row * APAD + c * 8] = *(const float4*)&AHV[(size_t)(mt * 128 + row) * 192 + c * 8];
  }
  int l15 = lane & 15, q = lane >> 4;
  int mh = (wv & 1) * 64, nh = (wv >> 1) * 64;
  const float invs192 = 0.07216878364870323f;
  floatx4 acc[4][4];
#pragma unroll
  for (int mi = 0; mi < 4; ++mi)
#pragma unroll
    for (int ni = 0; ni < 4; ++ni)
#pragma unroll
      for (int r = 0; r < 4; ++r) acc[mi][ni][r] = 0.f;
  for (int kc = 0; kc < 6; ++kc) {
    __syncthreads();
#pragma unroll
    for (int u = 0; u < 2; ++u) {
      int un = tid * 2 + u;
      int n = un >> 2, kk = (un & 3) * 8;
      *(float4*)&Bs[n * BPAD + kk] = *(const float4*)&B1T[(size_t)(n0 + n) * 192 + kc * 32 + kk];
    }
    __syncthreads();
    short8 a[4], bfr[4];
#pragma unroll
    for (int mi = 0; mi < 4; ++mi)
      a[mi] = *reinterpret_cast<const short8*>(&As[(mh + mi * 16 + l15) * APAD + kc * 32 + q * 8]);
#pragma unroll
    for (int ni = 0; ni < 4; ++ni)
      bfr[ni] = *reinterpret_cast<const short8*>(&Bs[(nh + ni * 16 + l15) * BPAD + q * 8]);
#pragma unroll
    for (int mi = 0; mi < 4; ++mi)
#pragma unroll
      for (int ni = 0; ni < 4; ++ni)
        acc[mi][ni] = __builtin_amdgcn_mfma_f32_16x16x32_bf16(a[mi], bfr[ni], acc[mi][ni], 0, 0, 0);
  }
  float c4v[4];
  if (n0 + nh < 256) {
#pragma unroll
    for (int ni = 0; ni < 4; ++ni) c4v[ni] = c4[n0 + nh + ni * 16 + l15];
  }
#pragma unroll
  for (int mi = 0; mi < 4; ++mi) {
#pragma unroll
    for (int r = 0; r < 4; ++r) {
      int row = mh + mi * 16 + q * 4 + r;
      int item = mt * 128 + row;
      int rf = rf_l[row];
#pragma unroll
      for (int ni = 0; ni < 4; ++ni) {
        int coln = n0 + nh + ni * 16 + l15;
        float o = acc[mi][ni][r];
        if (coln < 256) {
          P4s16[(size_t)item * 256 + coln] = f2bf((o + c4v[ni]) * invs192);
        } else if (coln < 448) {
          if (rf) Cg[(size_t)item * 192 + (coln - 256)] = o;
        } else {
          if (!rf) Cg[(size_t)item * 192 + (coln - 448)] = o;
        }
      }
    }
  }
}

// ---------------- per-(t,b) smalls: SQV, cbp, PROBC (reads AHV) ----------------
__global__ __launch_bounds__(256) void k5(
    const int* __restrict__ bg_index, const int* __restrict__ mem_resp,
    const unsigned short* __restrict__ AHV, const float* __restrict__ RQ,
    const float* __restrict__ QVG, const float* __restrict__ b_bg,
    const float* __restrict__ bgp, const float* __restrict__ V,
    const float* __restrict__ W_pred, const float* __restrict__ c0,
    float* __restrict__ SQVb, float* __restrict__ cbp, float* __restrict__ PROBC) {
  int tb = blockIdx.x;
  int tid = threadIdx.x;
  int lane = tid & 63, wv = tid >> 6;
  __shared__ float ahv[10 * 196];
  __shared__ float rql[4 * 196];
  __shared__ float bgpl[384];
  __shared__ int rf_s[10];
  __shared__ float cqb[4];
  if (tid < 10) { int g = bg_index[tb * 20 + tid]; rf_s[tid] = mem_resp[g]; }
  for (int i = tid; i < 384; i += 256) bgpl[i] = bgp[i];
  for (int i = tid; i < 768; i += 256) { int h = i / 192, c = i - h * 192; rql[h * 196 + c] = RQ[(size_t)tb * 768 + i]; }
  {
    const unsigned short* AH = &AHV[(size_t)tb * 10 * 192];
    for (int i = tid; i < 1920; i += 256) {
      int s = i / 192, c = i - 192 * s;
      ahv[s * 196 + c] = bf2f(AH[s * 192 + c]);
    }
  }
  if (tid < 4) {
    float s = 0.f;
    for (int d = 0; d < 64; ++d) s += QVG[(size_t)tb * 640 + tid * 64 + d] * b_bg[tid * 64 + d];
    cqb[tid] = s;
  }
  __syncthreads();
  const float invs192 = 0.07216878364870323f;
  for (int q = 0; q < 10; ++q) {
    float v = ahv[q * 196 + lane] * rql[wv * 196 + lane]
            + ahv[q * 196 + 64 + lane] * rql[wv * 196 + 64 + lane]
            + ahv[q * 196 + 128 + lane] * rql[wv * 196 + 128 + lane];
    v = wave_sum(v);
    if (lane == 0) SQVb[tb * 40 + wv * 10 + q] = (v + cqb[wv]) * invs192;
  }
  if (wv == 0) {
    for (int q = 0; q < 10; ++q) {
      int off = rf_s[q] ? 0 : 192;
      float v = ahv[q * 196 + lane] * bgpl[off + lane]
              + ahv[q * 196 + 64 + lane] * bgpl[off + 64 + lane]
              + ahv[q * 196 + 128 + lane] * bgpl[off + 128 + lane];
      v = wave_sum(v);
      if (lane == 0) cbp[tb * 10 + q] = v;
    }
  }
  if (wv == 1) {
    float v = V[tb * 128 + lane] * W_pred[384 + lane] + V[tb * 128 + 64 + lane] * W_pred[448 + lane];
    v = wave_sum(v);
    if (lane == 0) PROBC[tb] = v + c0[0];
  }
}

// ---------------- precompute history softmax weights ----------------
__global__ __launch_bounds__(64) void prep_pw(const float* S, const int* response,
                                              float* PW, float* PR) {
  int bt = blockIdx.x; int b = bt >> 7, t = bt & 127;
  int lane = threadIdx.x;
  size_t row = (size_t)bt * 128;
  float s0 = (lane == 0) ? 0.f : ((lane <= t) ? S[row + lane - 1] : -1e30f);
  float s1 = (lane + 64 <= t) ? S[row + lane + 63] : -1e30f;
  float m = wave_max(fmaxf(s0, s1));
  float e0 = (lane <= t) ? __expf(s0 - m) : 0.f;
  float e1 = (lane + 64 <= t) ? __expf(s1 - m) : 0.f;
  float inv = 1.f / wave_sum(e0 + e1);
  float r0 = (lane >= 1) ? (float)response[(lane - 1) * 64 + b] : 0.f;
  float r1 = (float)response[(lane + 63) * 64 + b];
  PW[row + lane] = e0 * inv;
  PW[row + 64 + lane] = e1 * inv;
  PR[row + lane] = e0 * inv * r0;
  PR[row + 64 + lane] = e1 * inv * r1;
}

// ---------------- sequential recurrence: 256 threads (4 waves) per b ----------------
// 4 phases/step; 4-wave barriers (half the skew of 8); fan-in width 4.
__global__ __launch_bounds__(256) void seq_kernel(
    const int* __restrict__ response, const unsigned short* __restrict__ P4s16,
    const float* __restrict__ SQVb, const float* __restrict__ Cg,
    const float* __restrict__ QVG, const float* __restrict__ cbp,
    const float* __restrict__ PROBC, const float* __restrict__ PW,
    const float* __restrict__ PR, const float* __restrict__ Hmix,
    const float* __restrict__ W_hh, const float* __restrict__ b_hh,
    const float* __restrict__ cgx, const float* __restrict__ uh,
    const float* __restrict__ W_pred, const float* __restrict__ heads_map,
    const float* __restrict__ dwv, float* __restrict__ out) {
  int b = blockIdx.x;
  int tid = threadIdx.x;
  int lane = tid & 63, wv = tid >> 6;      // 4 waves
  int cg3 = lane * 3;
  float hreg[32][3], wreg[16][3];
#pragma unroll
  for (int ii = 0; ii < 32; ++ii)
#pragma unroll
    for (int cc = 0; cc < 3; ++cc) hreg[ii][cc] = Hmix[(wv * 32 + ii) * 192 + cg3 + cc];
#pragma unroll
  for (int ii = 0; ii < 16; ++ii)
#pragma unroll
    for (int cc = 0; cc < 3; ++cc) wreg[ii][cc] = W_hh[(wv * 16 + ii) * 192 + cg3 + cc];
  float wph_reg[16], uh_reg[32];
  if (lane == 0) {
#pragma unroll
    for (int j = 0; j < 16; ++j) wph_reg[j] = W_pred[512 + wv * 16 + j];
#pragma unroll
    for (int ii = 0; ii < 32; ++ii) uh_reg[ii] = uh[wv * 32 + ii];
  }
  float bhh0 = 0.f, bhh1 = 0.f, bhh2 = 0.f;   // gh threads: tid 64..255 own c = tid-64 (192)
  if (tid >= 64) bhh0 = b_hh[tid - 64];
  float cgx0 = 0.f, cgx1 = 0.f, cgx2 = 0.f;
  if (tid < 64) { cgx0 = cgx[tid]; cgx1 = cgx[64 + tid]; cgx2 = cgx[128 + tid]; }
  (void)bhh1; (void)bhh2;
  float hmr = 0.f;
  if (tid >= 100 && tid < 104) hmr = heads_map[tid - 100];

  __shared__ float h_hist[128][64];
  __shared__ __align__(16) float PWl[128];
  __shared__ __align__(16) float PRl[128];
  __shared__ __align__(16) float h_cur[64];
  __shared__ float part_sc[4][40];
  __shared__ __align__(16) float e_l[40];
  __shared__ __align__(16) float inv_l[4];
  __shared__ __align__(16) float hisA[128];
  __shared__ float red8[4][128];
  __shared__ float redWg[4][192];
  __shared__ float redWh[4][192];
  __shared__ float gh_l[192];
  __shared__ float hwp_p[4], phis_p[4];
  __shared__ int resp_l[128];

  for (int i = tid; i < 128 * 64; i += 256) ((float*)h_hist)[i] = 0.f;
  if (tid < 64) h_cur[tid] = 0.f;
  if (tid >= 128) resp_l[tid - 128] = response[(tid - 128) * 64 + b];
  float dw0 = dwv[0], dw1 = dwv[1];

  // ---- prefetch state ----
  // score partial: lane p<40 of wave wv holds P4 frag for d = wv*16 .. +16
  int sc_off = 0;
  if (lane < 40) { int hh = lane / 10, s = lane - hh * 10; sc_off = s * 256 + hh * 64 + wv * 16; }
  short8 pf8a = {}, pf8b = {};
  if (lane < 40) {
    pf8a = *(const short8*)&P4s16[(size_t)b * 2560 + sc_off];
    pf8b = *(const short8*)&P4s16[(size_t)b * 2560 + sc_off + 8];
  }
  float pf_sqv = 0.f;                       // e threads: tid 216..255
  if (tid >= 216) pf_sqv = SQVb[b * 40 + (tid - 216)];
  float pf_cg0[10], pf_cg1[10], pf_cg2[10];
  float pf_gxA0 = 0.f, pf_gxA1 = 0.f, pf_gxA2 = 0.f, pf_gxB0 = 0.f, pf_gxB1 = 0.f, pf_gxB2 = 0.f;
  if (tid < 64) {
#pragma unroll
    for (int s = 0; s < 10; ++s) {
      size_t base = (size_t)(b * 10 + s) * 192;
      pf_cg0[s] = Cg[base + tid]; pf_cg1[s] = Cg[base + 64 + tid]; pf_cg2[s] = Cg[base + 128 + tid];
    }
    size_t gb = (size_t)b * 640 + 256;
    pf_gxA0 = QVG[gb + tid]; pf_gxA1 = QVG[gb + 64 + tid]; pf_gxA2 = QVG[gb + 128 + tid];
    pf_gxB0 = QVG[gb + 192 + tid]; pf_gxB1 = QVG[gb + 256 + tid]; pf_gxB2 = QVG[gb + 320 + tid];
  }
  float pf_cbp[10]; float pf_probc = 0.f;
  if (tid == 192) {
#pragma unroll
    for (int s = 0; s < 10; ++s) pf_cbp[s] = cbp[b * 10 + s];
    pf_probc = PROBC[b];
  }
  float4 pf_pw = make_float4(0, 0, 0, 0), pf_pr = pf_pw;
  if (tid >= 128 && tid < 160) pf_pw = *(const float4*)&PW[((size_t)(b * 128 + 0)) * 128 + 4 * (tid - 128)];
  else if (tid >= 160 && tid < 192) pf_pr = *(const float4*)&PR[((size_t)(b * 128 + 0)) * 128 + 4 * (tid - 160)];
  if (tid >= 128 && tid < 160) *(float4*)&PWl[4 * (tid - 128)] = pf_pw;
  else if (tid >= 160 && tid < 192) *(float4*)&PRl[4 * (tid - 160)] = pf_pr;
  if (tid >= 128 && tid < 160) pf_pw = *(const float4*)&PW[((size_t)(b * 128 + 1)) * 128 + 4 * (tid - 128)];
  else if (tid >= 160 && tid < 192) pf_pr = *(const float4*)&PR[((size_t)(b * 128 + 1)) * 128 + 4 * (tid - 160)];
  ldsbar();

  for (int t = 0; t < 128; ++t) {
    int tn = (t < 127) ? t + 1 : 127;
    int tbn = tn * 64 + b;
    // ===== phase A: partials (scores/gh/hwp) + history sums =====
    float4 ha = *(const float4*)&h_cur[wv * 16];
    float4 hb = *(const float4*)&h_cur[wv * 16 + 4];
    float4 hc4 = *(const float4*)&h_cur[wv * 16 + 8];
    float4 hd = *(const float4*)&h_cur[wv * 16 + 12];
    float hl[16] = {ha.x, ha.y, ha.z, ha.w, hb.x, hb.y, hb.z, hb.w,
                    hc4.x, hc4.y, hc4.z, hc4.w, hd.x, hd.y, hd.z, hd.w};
    if (lane < 40) {
      const unsigned short* p1 = (const unsigned short*)&pf8a;
      const unsigned short* p2 = (const unsigned short*)&pf8b;
      float v = 0.f;
#pragma unroll
      for (int j = 0; j < 8; ++j) v += hl[j] * bf2f(p1[j]);
#pragma unroll
      for (int j = 0; j < 8; ++j) v += hl[8 + j] * bf2f(p2[j]);
      part_sc[wv][lane] = v;
      pf8a = *(const short8*)&P4s16[(size_t)tbn * 2560 + sc_off];
      pf8b = *(const short8*)&P4s16[(size_t)tbn * 2560 + sc_off + 8];
    }
    {
      float l0 = 0.f, l1 = 0.f, l2 = 0.f;
#pragma unroll
      for (int ii = 0; ii < 16; ++ii) {
        l0 += hl[ii] * wreg[ii][0]; l1 += hl[ii] * wreg[ii][1]; l2 += hl[ii] * wreg[ii][2];
      }
      redWg[wv][cg3] = l0; redWg[wv][cg3 + 1] = l1; redWg[wv][cg3 + 2] = l2;
      if (lane == 0) {
        float hp = 0.f;
#pragma unroll
        for (int j = 0; j < 16; ++j) hp += hl[j] * wph_reg[j];
        hwp_p[wv] = hp;
      }
    }
    {
      int j0 = wv * 32;
      float aR = 0.f, aA = 0.f;
#pragma unroll
      for (int k = 0; k < 32; ++k) {
        float hv = h_hist[j0 + k][lane];
        aA += PWl[j0 + k] * hv; aR += PRl[j0 + k] * hv;
      }
      red8[wv][lane] = aR; red8[wv][64 + lane] = aA;
    }
    ldsbar();
    // ===== phase B: hisA; gh; e_l =====
    if (tid < 64) {
      float sR = red8[0][tid] + red8[1][tid] + red8[2][tid] + red8[3][tid];
      float sA = red8[0][64 + tid] + red8[1][64 + tid] + red8[2][64 + tid] + red8[3][64 + tid];
      hisA[tid] = sR; hisA[64 + tid] = sA - sR;
    } else {
      int c = tid - 64;
      float g = redWg[0][c] + redWg[1][c] + redWg[2][c] + redWg[3][c];
      gh_l[c] = g + bhh0;
      if (tid >= 216) {
        int p = tid - 216;
        float s = pf_sqv + part_sc[0][p] + part_sc[1][p] + part_sc[2][p] + part_sc[3][p];
        e_l[p] = __expf(s);   // no max-sub: scores O(1), fp32 exact enough
        pf_sqv = SQVb[tbn * 40 + p];
      }
    }
    ldsbar();
    // ===== phase C: redWh partials; phis partials; inv =====
    {
      float hA[32];
#pragma unroll
      for (int k = 0; k < 8; ++k) *(float4*)&hA[4 * k] = *(const float4*)&hisA[wv * 32 + 4 * k];
      float l0 = 0.f, l1 = 0.f, l2 = 0.f;
#pragma unroll
      for (int ii = 0; ii < 32; ++ii) {
        l0 += hA[ii] * hreg[ii][0]; l1 += hA[ii] * hreg[ii][1]; l2 += hA[ii] * hreg[ii][2];
      }
      redWh[wv][cg3] = l0; redWh[wv][cg3 + 1] = l1; redWh[wv][cg3 + 2] = l2;
      if (lane == 0) {
        float pp = 0.f;
#pragma unroll
        for (int ii = 0; ii < 32; ++ii) pp += hA[ii] * uh_reg[ii];
        phis_p[wv] = pp;
      }
    }
    if (tid >= 100 && tid < 104) {
      int h = tid - 100;
      float den = 0.f;
#pragma unroll
      for (int s = 0; s < 10; ++s) den += e_l[h * 10 + s];
      inv_l[h] = hmr / den;
    }
    ldsbar();
    // ===== phase D: GRU + out + PW/PR rotate =====
    if (tid < 64 || tid == 192) {
      float4 iv = *(const float4*)&inv_l[0];
      float ev[40];
#pragma unroll
      for (int qq = 0; qq < 10; ++qq) *(float4*)&ev[4 * qq] = *(const float4*)&e_l[4 * qq];
      float ws[10];
#pragma unroll
      for (int s = 0; s < 10; ++s)
        ws[s] = iv.x * ev[s] + iv.y * ev[10 + s] + iv.z * ev[20 + s] + iv.w * ev[30 + s];
      if (tid < 64) {
        float gxh0 = redWh[0][tid] + redWh[1][tid] + redWh[2][tid] + redWh[3][tid];
        float gxh1 = redWh[0][64 + tid] + redWh[1][64 + tid] + redWh[2][64 + tid] + redWh[3][64 + tid];
        float gxh2 = redWh[0][128 + tid] + redWh[1][128 + tid] + redWh[2][128 + tid] + redWh[3][128 + tid];
        float gbg0 = 0.f, gbg1 = 0.f, gbg2 = 0.f;
#pragma unroll
        for (int s = 0; s < 10; ++s) {
          gbg0 += ws[s] * pf_cg0[s]; gbg1 += ws[s] * pf_cg1[s]; gbg2 += ws[s] * pf_cg2[s];
        }
        int rn = resp_l[t];
        float xr = dw0 * gbg0 + dw1 * gxh0 + (rn ? pf_gxA0 : pf_gxB0) + cgx0;
        float xz = dw0 * gbg1 + dw1 * gxh1 + (rn ? pf_gxA1 : pf_gxB1) + cgx1;
        float xn = dw0 * gbg2 + dw1 * gxh2 + (rn ? pf_gxA2 : pf_gxB2) + cgx2;
        float hr = gh_l[tid], hz = gh_l[64 + tid], hn = gh_l[128 + tid];
        float r = 1.f / (1.f + __expf(-(xr + hr)));
        float z = 1.f / (1.f + __expf(-(xz + hz)));
        float n = tanhf(xn + r * hn);
        float hnew = (1.f - z) * n + z * h_cur[tid];
        h_cur[tid] = hnew;
        if (t < 127) h_hist[t + 1][tid] = hnew;
#pragma unroll
        for (int s = 0; s < 10; ++s) {
          size_t base = (size_t)(tbn * 10 + s) * 192;
          pf_cg0[s] = Cg[base + tid]; pf_cg1[s] = Cg[base + 64 + tid]; pf_cg2[s] = Cg[base + 128 + tid];
        }
        size_t gb = (size_t)tbn * 640 + 256;
        pf_gxA0 = QVG[gb + tid]; pf_gxA1 = QVG[gb + 64 + tid]; pf_gxA2 = QVG[gb + 128 + tid];
        pf_gxB0 = QVG[gb + 192 + tid]; pf_gxB1 = QVG[gb + 256 + tid]; pf_gxB2 = QVG[gb + 320 + tid];
      } else {
        float pbg = 0.f;
#pragma unroll
        for (int s = 0; s < 10; ++s) pbg += ws[s] * pf_cbp[s];
        float ph = phis_p[0] + phis_p[1] + phis_p[2] + phis_p[3];
        float hw = hwp_p[0] + hwp_p[1] + hwp_p[2] + hwp_p[3];
        out[b * 128 + t] = dw0 * pbg + dw1 * ph + hw + pf_probc;
#pragma unroll
        for (int s = 0; s < 10; ++s) pf_cbp[s] = cbp[tbn * 10 + s];
        pf_probc = PROBC[tbn];
      }
    } else if (tid >= 128 && tid < 192) {
      if (tid < 160) *(float4*)&PWl[4 * (tid - 128)] = pf_pw;
      else *(float4*)&PRl[4 * (tid - 160)] = pf_pr;
      int rn2 = (t + 2 < 128) ? t + 2 : 127;
      if (tid < 160) pf_pw = *(const float4*)&PW[((size_t)(b * 128 + rn2)) * 128 + 4 * (tid - 128)];
      else pf_pr = *(const float4*)&PR[((size_t)(b * 128 + rn2)) * 128 + 4 * (tid - 160)];
    }
    ldsbar();
  }
}

// ---------------- launch ----------------
extern "C" void kernel_launch(void* const* d_in, const int* in_sizes, int n_in,
                              void* d_out, int out_size, void* d_ws, size_t ws_size,
                              hipStream_t stream) {
  const int* prob_id      = (const int*)d_in[0];
  const int* skills       = (const int*)d_in[1];
  const int* response     = (const int*)d_in[2];
  const int* bg_index     = (const int*)d_in[3];
  const int* mem_prob_ids = (const int*)d_in[4];
  const int* mem_resp     = (const int*)d_in[5];
  const int* mem_concepts = (const int*)d_in[6];
  const float* states_mem  = (const float*)d_in[7];
  const float* concept_emb = (const float*)d_in[8];
  const float* prob_emb    = (const float*)d_in[9];
  const float* W_pred   = (const float*)d_in[10];
  const float* b_pred   = (const float*)d_in[11];
  const float* W_ih     = (const float*)d_in[12];
  const float* W_hh     = (const float*)d_in[13];
  const float* b_ih     = (const float*)d_in[14];
  const float* b_hh     = (const float*)d_in[15];
  const float* W_batch  = (const float*)d_in[16];
  const float* b_batch  = (const float*)d_in[17];
  const float* W_bg     = (const float*)d_in[18];
  const float* b_bg     = (const float*)d_in[19];
  const float* W_bgint  = (const float*)d_in[20];
  const float* b_bgint  = (const float*)d_in[21];
  const float* W_hisint = (const float*)d_in[22];
  const float* b_hisint = (const float*)d_in[23];
  const float* W_inmap  = (const float*)d_in[24];
  const float* b_inmap  = (const float*)d_in[25];
  const float* dir_w    = (const float*)d_in[26];
  const float* heads_map= (const float*)d_in[27];
  float* out = (float*)d_out;

  float* w = (float*)d_ws;
  size_t off = 0;
  auto alloc = [&](size_t n) { float* p = w + off; off += (n + 3) & ~(size_t)3; return p; };
  float* M12    = alloc(640 * 192);
  unsigned short* B1T = (unsigned short*)alloc(640 * 192 / 2);
  float* Hmix   = alloc(128 * 192);
  float* WgT    = alloc(4 * 192 * 64);
  float* BQG    = alloc(128 * 640);
  float* biasQG = alloc(640);
  float* c4     = alloc(256);
  float* cgx    = alloc(192);
  float* uh     = alloc(128);
  float* bgp    = alloc(384);
  float* c0     = alloc(1);
  float* dwv    = alloc(2);
  float* V      = alloc((size_t)8192 * 128);
  float* VT     = alloc((size_t)64 * 128 * 128);
  float* QVG    = alloc((size_t)8192 * 640);
  float* RQ     = alloc((size_t)8192 * 768);
  float* S      = alloc((size_t)64 * 128 * 128);   // becomes PW in-place
  float* PR     = alloc((size_t)64 * 128 * 128);
  unsigned short* AHV = (unsigned short*)alloc((size_t)NITEM * 192 / 2);
  unsigned short* P4s16 = (unsigned short*)alloc((size_t)NITEM * 256 / 2);
  float* Cg     = alloc((size_t)NITEM * 192);
  float* SQVb   = alloc((size_t)8192 * 40);
  float* cbp    = alloc((size_t)NITEM);
  float* PROBC  = alloc(8192);
  (void)ws_size; (void)in_sizes; (void)n_in; (void)out_size;

  build_v<<<8192, 64, 0, stream>>>(prob_id, skills, concept_emb, prob_emb, V, VT);
  gather_ahv<<<NITEM * 96 / 256, 256, 0, stream>>>(bg_index, mem_prob_ids, mem_concepts,
      states_mem, concept_emb, prob_emb, AHV);
  gemm_f32<<<dim3(3, 10, 1), 256, 0, stream>>>(W_inmap, W_ih, M12, nullptr,
      640, 192, 256, 256, 192, 192, 0, 0, 0, 1.0f);
  k_small<<<1095, 256, 0, stream>>>(W_batch, W_bg, b_bg, W_bgint, b_bgint, W_hisint, b_hisint,
      W_ih, b_ih, b_inmap, W_pred, b_pred, dir_w, b_batch, M12, B1T, Hmix, WgT, BQG, biasQG,
      c4, cgx, uh, bgp, c0, dwv);
  gemm_f32<<<dim3(10, 128, 1), 256, 0, stream>>>(V, BQG, QVG, biasQG,
      8192, 640, 128, 128, 640, 640, 0, 0, 0, 1.0f);
  gemm_f32<<<dim3(3, 128, 4), 256, 0, stream>>>(QVG, WgT, RQ, nullptr,
      8192, 192, 64, 640, 192, 768, 64, 12288, 192, 1.0f);
  gemm_f32<<<dim3(2, 2, 64), 256, 0, stream>>>(V, VT, S, nullptr,
      128, 128, 128, 8192, 128, 128, 128, 16384, 16384, 0.08838834764831845f);
  prep_pw<<<8192, 64, 0, stream>>>(S, response, S, PR);
  big_gemm<<<dim3(640, 5), 256, 0, stream>>>(bg_index, mem_resp, AHV, B1T, c4, P4s16, Cg);
  k5<<<8192, 256, 0, stream>>>(bg_index, mem_resp, AHV, RQ, QVG, b_bg, bgp, V, W_pred, c0,
      SQVb, cbp, PROBC);
  seq_kernel<<<64, 256, 0, stream>>>(response, P4s16, SQVb, Cg, QVG, cbp, PROBC,
      S, PR, Hmix, W_hh, b_hh, cgx, uh, W_pred, heads_map, dwv, out);
}

// Round 9
// 751.722 us; speedup vs baseline: 1.1830x; 1.1830x over previous
//
#include <hip/hip_runtime.h>
#include <hip/hip_bf16.h>

// ---------------- constants ----------------
#define TT 128
#define BB 64
#define NITEM (TT*BB*SEE)
#define SEE 10
typedef __attribute__((ext_vector_type(8))) short short8;    // 8 bf16
typedef __attribute__((ext_vector_type(4))) float floatx4;   // MFMA acc

static __device__ __forceinline__ float wave_sum(float v) {
  v += __shfl_xor(v, 32); v += __shfl_xor(v, 16); v += __shfl_xor(v, 8);
  v += __shfl_xor(v, 4);  v += __shfl_xor(v, 2);  v += __shfl_xor(v, 1);
  return v;
}
static __device__ __forceinline__ float wave_max(float v) {
  v = fmaxf(v, __shfl_xor(v, 32)); v = fmaxf(v, __shfl_xor(v, 16)); v = fmaxf(v, __shfl_xor(v, 8));
  v = fmaxf(v, __shfl_xor(v, 4));  v = fmaxf(v, __shfl_xor(v, 2));  v = fmaxf(v, __shfl_xor(v, 1));
  return v;
}
static __device__ __forceinline__ unsigned short f2bf(float x) {
  __hip_bfloat16 h = __float2bfloat16(x);
  return *reinterpret_cast<unsigned short*>(&h);
}
static __device__ __forceinline__ float bf2f(unsigned short u) {
  unsigned v = ((unsigned)u) << 16;
  return __builtin_bit_cast(float, v);
}
static __device__ __forceinline__ unsigned int pack2(float lo, float hi) {
  return (unsigned int)f2bf(lo) | ((unsigned int)f2bf(hi) << 16);
}
// LDS-only barrier: does not drain outstanding global loads (vmcnt).
static __device__ __forceinline__ void ldsbar() {
  asm volatile("s_waitcnt lgkmcnt(0)" ::: "memory");
  __builtin_amdgcn_s_barrier();
  asm volatile("" ::: "memory");
}

// ---------------- build V (fp32 + bf16) and V^T per b ----------------
__global__ void build_v(const int* __restrict__ prob_id, const int* __restrict__ skills,
                        const float* __restrict__ concept_emb, const float* __restrict__ prob_emb,
                        float* __restrict__ V, float* __restrict__ VT,
                        unsigned short* __restrict__ V16) {
  int tb = blockIdx.x; int t = tb >> 6, b = tb & 63; int d = threadIdx.x;
  int pid = prob_id[tb];
  float pr = pid ? prob_emb[(pid - 1) * 64 + d] : 0.0f;
  int cnt = 0; float sum = 0.0f;
#pragma unroll
  for (int c = 0; c < 4; ++c) {
    int sk = skills[tb * 4 + c];
    if (sk) { ++cnt; sum += concept_emb[(sk - 1) * 64 + d]; }
  }
  float mean = sum / (float)(cnt ? cnt : 1);
  V[tb * 128 + d] = mean;
  V[tb * 128 + 64 + d] = pr;
  V16[tb * 128 + d] = f2bf(mean);
  V16[tb * 128 + 64 + d] = f2bf(pr);
  VT[b * 16384 + d * 128 + t] = mean;
  VT[b * 16384 + (64 + d) * 128 + t] = pr;
}

// ---------------- massively parallel bf16 gather: AHV[item][192] ----------------
__global__ __launch_bounds__(256) void gather_ahv(
    const int* __restrict__ bg_index, const int* __restrict__ mem_prob_ids,
    const int* __restrict__ mem_concepts, const float* __restrict__ states_mem,
    const float* __restrict__ concept_emb, const float* __restrict__ prob_emb,
    unsigned short* __restrict__ AHV) {
  int gid = blockIdx.x * 256 + threadIdx.x;      // NITEM*96 threads
  int item = gid / 96, c2 = gid - 96 * item; int d = 2 * c2;
  int t = item / 640; int rem = item - t * 640; int b = rem / 10; int s = rem - b * 10;
  int g = bg_index[(t * 64 + b) * 20 + s];
  float v0, v1;
  if (d < 64) {
    float2 sv = *(const float2*)&states_mem[g * 64 + d];
    v0 = sv.x; v1 = sv.y;
  } else if (d < 128) {
    int dd = d - 64; float s0 = 0.f, s1 = 0.f; int cnt = 0;
#pragma unroll
    for (int c = 0; c < 4; ++c) {
      int sk = mem_concepts[g * 4 + c];
      if (sk) { ++cnt; float2 e = *(const float2*)&concept_emb[(sk - 1) * 64 + dd]; s0 += e.x; s1 += e.y; }
    }
    float inv = 1.0f / (float)(cnt ? cnt : 1);
    v0 = s0 * inv; v1 = s1 * inv;
  } else {
    int dd = d - 128; int pid = mem_prob_ids[g];
    if (pid) { float2 pv = *(const float2*)&prob_emb[(pid - 1) * 64 + dd]; v0 = pv.x; v1 = pv.y; }
    else { v0 = 0.f; v1 = 0.f; }
  }
  *(unsigned int*)&AHV[(size_t)item * 192 + d] = pack2(v0, v1);
}

// ---------------- generic fp32 GEMM (used for M12 and S only) ----------------
__global__ __launch_bounds__(256) void gemm_f32(
    const float* __restrict__ A, const float* __restrict__ B, float* __restrict__ C,
    const float* __restrict__ bias, int M, int N, int K,
    int lda, int ldb, int ldc, long sA, long sB, long sC, float scale) {
  __shared__ __align__(16) float As[64 * 36];
  __shared__ __align__(16) float Bs[32 * 64];
  const float* Ab = A + (long)blockIdx.z * sA;
  const float* Bb = B + (long)blockIdx.z * sB;
  float* Cb = C + (long)blockIdx.z * sC;
  int m0 = blockIdx.y * 64, n0 = blockIdx.x * 64;
  int tid = threadIdx.x;
  int ti = tid & 15, tj = tid >> 4;
  float acc[4][4] = {};
  for (int kc = 0; kc < K; kc += 32) {
#pragma unroll
    for (int p = 0; p < 2; ++p) {
      int q = tid + 256 * p;
      int row = q >> 3, kq = q & 7;
      *(float4*)&As[row * 36 + 4 * kq] = *(const float4*)&Ab[(size_t)(m0 + row) * lda + kc + 4 * kq];
    }
#pragma unroll
    for (int p = 0; p < 2; ++p) {
      int q = tid + 256 * p;
      int k = q >> 4, nq = q & 15;
      *(float4*)&Bs[k * 64 + 4 * nq] = *(const float4*)&Bb[(size_t)(kc + k) * ldb + n0 + 4 * nq];
    }
    __syncthreads();
#pragma unroll
    for (int k4 = 0; k4 < 8; ++k4) {
      float4 av[4], bv[4];
#pragma unroll
      for (int m = 0; m < 4; ++m) av[m] = *(const float4*)&As[(ti + 16 * m) * 36 + 4 * k4];
#pragma unroll
      for (int kk = 0; kk < 4; ++kk) bv[kk] = *(const float4*)&Bs[(4 * k4 + kk) * 64 + 4 * tj];
#pragma unroll
      for (int m = 0; m < 4; ++m) {
        const float* ap = (const float*)&av[m];
#pragma unroll
        for (int kk = 0; kk < 4; ++kk) {
          float a = ap[kk];
          acc[m][0] += a * bv[kk].x; acc[m][1] += a * bv[kk].y;
          acc[m][2] += a * bv[kk].z; acc[m][3] += a * bv[kk].w;
        }
      }
    }
    __syncthreads();
  }
  float4 bq = make_float4(0.f, 0.f, 0.f, 0.f);
  if (bias) bq = *(const float4*)&bias[n0 + 4 * tj];
#pragma unroll
  for (int m = 0; m < 4; ++m) {
    int row = m0 + ti + 16 * m;
    float4 o;
    o.x = acc[m][0] * scale + bq.x; o.y = acc[m][1] * scale + bq.y;
    o.z = acc[m][2] * scale + bq.z; o.w = acc[m][3] * scale + bq.w;
    *(float4*)&Cb[(size_t)row * ldc + n0 + 4 * tj] = o;
  }
}

// ---------------- small weight folds (needs M12) ----------------
// BRQT (bf16, [1408 n][128 k]): cols 0..255 QV, 256..639 GXV, 640..1407 RQ.
__global__ __launch_bounds__(256) void k_small(
    const float* __restrict__ W_batch, const float* __restrict__ W_bg, const float* __restrict__ b_bg,
    const float* __restrict__ W_bgint, const float* __restrict__ b_bgint,
    const float* __restrict__ W_hisint, const float* __restrict__ b_hisint,
    const float* __restrict__ W_ih, const float* __restrict__ b_ih, const float* __restrict__ b_inmap,
    const float* __restrict__ W_pred, const float* __restrict__ b_pred, const float* __restrict__ dir_w,
    const float* __restrict__ b_batch,
    const float* __restrict__ M12, unsigned short* __restrict__ B1T, float* __restrict__ Hmix,
    unsigned short* __restrict__ BRQT, float* __restrict__ bias_all,
    float* __restrict__ c4, float* __restrict__ cgx, float* __restrict__ uh,
    float* __restrict__ bgp, float* __restrict__ c0, float* __restrict__ dwv) {
  int idx = blockIdx.x * 256 + threadIdx.x;
  const int R0 = 49152, R1 = 86016, R2 = 122880, R3 = 147456, R4 = 180224,
            R5 = 229376, R6 = 327680, R7 = 327936, R8 = 328128, R9 = 328256,
            R10 = 328640, R11 = 328641, R12 = 328643, R13 = 330051;
  if (idx < R0) {            // B1T P4 section
    int k = idx >> 8, n = idx & 255; int h = n >> 6, i = n & 63;
    float s = 0.f;
    for (int d = 0; d < 64; ++d) s += W_bg[h * 12288 + k * 64 + d] * W_batch[h * 12288 + i * 64 + d];
    B1T[n * 192 + k] = f2bf(s);
  } else if (idx < R1) {     // B1T Wmix top
    int r = idx - R0; int k = r / 192, c = r - k * 192;
    float s = 0.f;
    for (int j = 0; j < 384; ++j) s += W_bgint[k * 384 + j] * M12[j * 192 + c];
    B1T[(256 + c) * 192 + k] = f2bf(s);
  } else if (idx < R2) {     // B1T Wmix bottom
    int r = idx - R1; int k = r / 192, c = r - k * 192;
    float s = 0.f;
    for (int j = 0; j < 384; ++j) s += W_bgint[(192 + k) * 384 + j] * M12[j * 192 + c];
    B1T[(448 + c) * 192 + k] = f2bf(s);
  } else if (idx < R3) {     // Hmix
    int r = idx - R2; int i = r / 192, c = r - i * 192;
    float s = 0.f;
    for (int j = 0; j < 384; ++j) s += W_hisint[i * 384 + j] * M12[j * 192 + c];
    Hmix[i * 192 + c] = s;
  } else if (idx < R4) {     // BRQT QV section: n<256
    int r = idx - R3; int n = r >> 7, j = r & 127; int h = n >> 6, d = n & 63;
    BRQT[n * 128 + j] = f2bf(W_batch[h * 12288 + (64 + j) * 64 + d]);
  } else if (idx < R5) {     // BRQT GXV section
    int r = idx - R4; int c = r >> 7, j = r & 127;
    float v = (c < 192) ? M12[(384 + j) * 192 + c] : M12[(512 + j) * 192 + (c - 192)];
    BRQT[(256 + c) * 128 + j] = f2bf(v);
  } else if (idx < R6) {     // BRQT RQ section: n = h*192+k
    int r = idx - R5; int n = r >> 7, j = r & 127; int h = n / 192, k = n - h * 192;
    float s = 0.f;
    for (int d = 0; d < 64; ++d) s += W_batch[h * 12288 + (64 + j) * 64 + d] * W_bg[h * 12288 + k * 64 + d];
    BRQT[(640 + n) * 128 + j] = f2bf(s);
  } else if (idx < R7) {     // c4
    int n = idx - R6; int h = n >> 6, i = n & 63;
    float s = 0.f;
    for (int d = 0; d < 64; ++d) s += W_batch[h * 12288 + i * 64 + d] * b_bg[h * 64 + d];
    c4[n] = s;
  } else if (idx < R8) {     // cgx
    int c = idx - R7;
    float e0 = __expf(dir_w[0]), e1 = __expf(dir_w[1]);
    float dw0 = e0 / (e0 + e1), dw1 = e1 / (e0 + e1);
    float s = b_ih[c];
    for (int i = 0; i < 256; ++i) s += b_inmap[i] * W_ih[i * 192 + c];
    for (int k = 0; k < 384; ++k) s += (dw0 * b_bgint[k] + dw1 * b_hisint[k]) * M12[k * 192 + c];
    cgx[c] = s;
  } else if (idx < R9) {     // uh
    int i = idx - R8;
    float s = 0.f;
    for (int j = 0; j < 384; ++j) s += W_hisint[i * 384 + j] * W_pred[j];
    uh[i] = s;
  } else if (idx < R10) {    // bgp
    int k = idx - R9;
    float s = 0.f;
    for (int j = 0; j < 384; ++j) s += W_bgint[k * 384 + j] * W_pred[j];
    bgp[k] = s;
  } else if (idx < R11) {    // c0
    float e0 = __expf(dir_w[0]), e1 = __expf(dir_w[1]);
    float dw0 = e0 / (e0 + e1), dw1 = e1 / (e0 + e1);
    float s = b_pred[0];
    for (int k = 0; k < 384; ++k) s += (dw0 * b_bgint[k] + dw1 * b_hisint[k]) * W_pred[k];
    c0[0] = s;
  } else if (idx < R12) {    // dwv
    float e0 = __expf(dir_w[0]), e1 = __expf(dir_w[1]);
    dwv[idx - R11] = (idx == R11) ? e0 / (e0 + e1) : e1 / (e0 + e1);
  } else if (idx < R13) {    // bias_all[1408]
    int i = idx - R12;
    float v = 0.f;
    if (i < 256) v = b_batch[i];
    else if (i >= 640) {
      int n = i - 640; int h = n / 192, k = n - h * 192;
      float s = 0.f;
      for (int d = 0; d < 64; ++d) s += b_batch[h * 64 + d] * W_bg[h * 12288 + k * 64 + d];
      v = s;
    }
    bias_all[i] = v;
  }
}

// ---------------- QVR = V16 @ BRQT^T + bias (bf16 MFMA) ----------------
// M=8192 (grid.x=64 tiles), N=1408 (grid.y=11 tiles), K=128.
#define VPAD 136
#define BPAD 40
__global__ __launch_bounds__(256) void mfma_qvr(
    const unsigned short* __restrict__ V16, const unsigned short* __restrict__ BRQT,
    const float* __restrict__ bias_all, float* __restrict__ QVR) {
  __shared__ unsigned short As[128 * VPAD];
  __shared__ unsigned short Bs[128 * BPAD];
  int mt = blockIdx.x, ntt = blockIdx.y;
  int n0 = ntt * 128;
  int tid = threadIdx.x;
  int lane = tid & 63, wv = tid >> 6;
  for (int i = tid; i < 128 * 16; i += 256) {
    int row = i >> 4, c = i & 15;
    *(float4*)&As[row * VPAD + c * 8] = *(const float4*)&V16[(size_t)(mt * 128 + row) * 128 + c * 8];
  }
  int l15 = lane & 15, q = lane >> 4;
  int mh = (wv & 1) * 64, nh = (wv >> 1) * 64;
  floatx4 acc[4][4];
#pragma unroll
  for (int mi = 0; mi < 4; ++mi)
#pragma unroll
    for (int ni = 0; ni < 4; ++ni)
#pragma unroll
      for (int r = 0; r < 4; ++r) acc[mi][ni][r] = 0.f;
  for (int kc = 0; kc < 4; ++kc) {
    __syncthreads();
#pragma unroll
    for (int u = 0; u < 2; ++u) {
      int un = tid * 2 + u;
      int n = un >> 2, kk = (un & 3) * 8;
      *(float4*)&Bs[n * BPAD + kk] = *(const float4*)&BRQT[(size_t)(n0 + n) * 128 + kc * 32 + kk];
    }
    __syncthreads();
    short8 a[4], bfr[4];
#pragma unroll
    for (int mi = 0; mi < 4; ++mi)
      a[mi] = *reinterpret_cast<const short8*>(&As[(mh + mi * 16 + l15) * VPAD + kc * 32 + q * 8]);
#pragma unroll
    for (int ni = 0; ni < 4; ++ni)
      bfr[ni] = *reinterpret_cast<const short8*>(&Bs[(nh + ni * 16 + l15) * BPAD + q * 8]);
#pragma unroll
    for (int mi = 0; mi < 4; ++mi)
#pragma unroll
      for (int ni = 0; ni < 4; ++ni)
        acc[mi][ni] = __builtin_amdgcn_mfma_f32_16x16x32_bf16(a[mi], bfr[ni], acc[mi][ni], 0, 0, 0);
  }
  float bv[4];
#pragma unroll
  for (int ni = 0; ni < 4; ++ni) bv[ni] = bias_all[n0 + nh + ni * 16 + l15];
#pragma unroll
  for (int mi = 0; mi < 4; ++mi) {
#pragma unroll
    for (int r = 0; r < 4; ++r) {
      int row = mh + mi * 16 + q * 4 + r;
      size_t item = (size_t)(mt * 128 + row);
#pragma unroll
      for (int ni = 0; ni < 4; ++ni) {
        int coln = n0 + nh + ni * 16 + l15;
        QVR[item * 1408 + coln] = acc[mi][ni][r] + bv[ni];
      }
    }
  }
}

// ---------------- big GEMM via bf16 MFMA (R7 structure: nt loop) ----------------
#define APAD 200
__global__ __launch_bounds__(256) void big_gemm(
    const int* __restrict__ bg_index, const int* __restrict__ mem_resp,
    const unsigned short* __restrict__ AHV, const unsigned short* __restrict__ B1T,
    const float* __restrict__ c4, unsigned short* __restrict__ P4s16, float* __restrict__ Cg) {
  __shared__ unsigned short As[128 * APAD];
  __shared__ unsigned short Bs[128 * BPAD];
  __shared__ int rf_l[128];
  int mt = blockIdx.x;
  int tid = threadIdx.x;
  int lane = tid & 63, wv = tid >> 6;
  if (tid < 128) {
    int item = mt * 128 + tid;
    int t = item / 640; int rem = item - t * 640; int b = rem / 10; int s = rem - b * 10;
    int g = bg_index[(t * 64 + b) * 20 + s];
    rf_l[tid] = mem_resp[g];
  }
  for (int i = tid; i < 128 * 24; i += 256) {
    int row = i / 24, c = i - 24 * row;
    *(float4*)&As[row * APAD + c * 8] = *(const float4*)&AHV[(size_t)(mt * 128 + row) * 192 + c * 8];
  }
  int l15 = lane & 15, q = lane >> 4;
  int mh = (wv & 1) * 64, nh = (wv >> 1) * 64;
  const float invs192 = 0.07216878364870323f;
  for (int nt = 0; nt < 5; ++nt) {
    int n0 = nt * 128;
    floatx4 acc[4][4];
#pragma unroll
    for (int mi = 0; mi < 4; ++mi)
#pragma unroll
      for (int ni = 0; ni < 4; ++ni)
#pragma unroll
        for (int r = 0; r < 4; ++r) acc[mi][ni][r] = 0.f;
    for (int kc = 0; kc < 6; ++kc) {
      __syncthreads();
#pragma unroll
      for (int u = 0; u < 2; ++u) {
        int un = tid * 2 + u;
        int n = un >> 2, kk = (un & 3) * 8;
        *(float4*)&Bs[n * BPAD + kk] = *(const float4*)&B1T[(size_t)(n0 + n) * 192 + kc * 32 + kk];
      }
      __syncthreads();
      short8 a[4], bfr[4];
#pragma unroll
      for (int mi = 0; mi < 4; ++mi)
        a[mi] = *reinterpret_cast<const short8*>(&As[(mh + mi * 16 + l15) * APAD + kc * 32 + q * 8]);
#pragma unroll
      for (int ni = 0; ni < 4; ++ni)
        bfr[ni] = *reinterpret_cast<const short8*>(&Bs[(nh + ni * 16 + l15) * BPAD + q * 8]);
#pragma unroll
      for (int mi = 0; mi < 4; ++mi)
#pragma unroll
        for (int ni = 0; ni < 4; ++ni)
          acc[mi][ni] = __builtin_amdgcn_mfma_f32_16x16x32_bf16(a[mi], bfr[ni], acc[mi][ni], 0, 0, 0);
    }
    float c4v[4];
    if (n0 + nh < 256) {
#pragma unroll
      for (int ni = 0; ni < 4; ++ni) c4v[ni] = c4[n0 + nh + ni * 16 + l15];
    }
#pragma unroll
    for (int mi = 0; mi < 4; ++mi) {
#pragma unroll
      for (int r = 0; r < 4; ++r) {
        int row = mh + mi * 16 + q * 4 + r;
        int item = mt * 128 + row;
        int rf = rf_l[row];
#pragma unroll
        for (int ni = 0; ni < 4; ++ni) {
          int coln = n0 + nh + ni * 16 + l15;
          float o = acc[mi][ni][r];
          if (coln < 256) {
            P4s16[(size_t)item * 256 + coln] = f2bf((o + c4v[ni]) * invs192);
          } else if (coln < 448) {
            if (rf) Cg[(size_t)item * 192 + (coln - 256)] = o;
          } else {
            if (!rf) Cg[(size_t)item * 192 + (coln - 448)] = o;
          }
        }
      }
    }
  }
}

// ---------------- per-(t,b) smalls: SQV, cbp, PROBC ----------------
__global__ __launch_bounds__(256) void k5(
    const int* __restrict__ bg_index, const int* __restrict__ mem_resp,
    const unsigned short* __restrict__ AHV, const float* __restrict__ QVR,
    const float* __restrict__ b_bg, const float* __restrict__ bgp, const float* __restrict__ V,
    const float* __restrict__ W_pred, const float* __restrict__ c0,
    float* __restrict__ SQVb, float* __restrict__ cbp, float* __restrict__ PROBC) {
  int tb = blockIdx.x;
  int tid = threadIdx.x;
  int lane = tid & 63, wv = tid >> 6;
  __shared__ float ahv[10 * 196];
  __shared__ float rql[4 * 196];
  __shared__ float bgpl[384];
  __shared__ int rf_s[10];
  __shared__ float cqb[4];
  if (tid < 10) { int g = bg_index[tb * 20 + tid]; rf_s[tid] = mem_resp[g]; }
  for (int i = tid; i < 384; i += 256) bgpl[i] = bgp[i];
  for (int i = tid; i < 768; i += 256) { int h = i / 192, c = i - h * 192; rql[h * 196 + c] = QVR[(size_t)tb * 1408 + 640 + i]; }
  {
    const unsigned short* AH = &AHV[(size_t)tb * 10 * 192];
    for (int i = tid; i < 1920; i += 256) {
      int s = i / 192, c = i - 192 * s;
      ahv[s * 196 + c] = bf2f(AH[s * 192 + c]);
    }
  }
  if (tid < 4) {
    float s = 0.f;
    for (int d = 0; d < 64; ++d) s += QVR[(size_t)tb * 1408 + tid * 64 + d] * b_bg[tid * 64 + d];
    cqb[tid] = s;
  }
  __syncthreads();
  const float invs192 = 0.07216878364870323f;
  for (int q = 0; q < 10; ++q) {
    float v = ahv[q * 196 + lane] * rql[wv * 196 + lane]
            + ahv[q * 196 + 64 + lane] * rql[wv * 196 + 64 + lane]
            + ahv[q * 196 + 128 + lane] * rql[wv * 196 + 128 + lane];
    v = wave_sum(v);
    if (lane == 0) SQVb[tb * 40 + wv * 10 + q] = (v + cqb[wv]) * invs192;
  }
  if (wv == 0) {
    for (int q = 0; q < 10; ++q) {
      int off = rf_s[q] ? 0 : 192;
      float v = ahv[q * 196 + lane] * bgpl[off + lane]
              + ahv[q * 196 + 64 + lane] * bgpl[off + 64 + lane]
              + ahv[q * 196 + 128 + lane] * bgpl[off + 128 + lane];
      v = wave_sum(v);
      if (lane == 0) cbp[tb * 10 + q] = v;
    }
  }
  if (wv == 1) {
    float v = V[tb * 128 + lane] * W_pred[384 + lane] + V[tb * 128 + 64 + lane] * W_pred[448 + lane];
    v = wave_sum(v);
    if (lane == 0) PROBC[tb] = v + c0[0];
  }
}

// ---------------- precompute history softmax weights ----------------
__global__ __launch_bounds__(64) void prep_pw(const float* S, const int* response,
                                              float* PW, float* PR) {
  int bt = blockIdx.x; int b = bt >> 7, t = bt & 127;
  int lane = threadIdx.x;
  size_t row = (size_t)bt * 128;
  float s0 = (lane == 0) ? 0.f : ((lane <= t) ? S[row + lane - 1] : -1e30f);
  float s1 = (lane + 64 <= t) ? S[row + lane + 63] : -1e30f;
  float m = wave_max(fmaxf(s0, s1));
  float e0 = (lane <= t) ? __expf(s0 - m) : 0.f;
  float e1 = (lane + 64 <= t) ? __expf(s1 - m) : 0.f;
  float inv = 1.f / wave_sum(e0 + e1);
  float r0 = (lane >= 1) ? (float)response[(lane - 1) * 64 + b] : 0.f;
  float r1 = (float)response[(lane + 63) * 64 + b];
  PW[row + lane] = e0 * inv;
  PW[row + 64 + lane] = e1 * inv;
  PR[row + lane] = e0 * inv * r0;
  PR[row + 64 + lane] = e1 * inv * r1;
}

// ---------------- sequential recurrence: R7 512-thread structure ----------------
__global__ __launch_bounds__(512) void seq_kernel(
    const int* __restrict__ response, const unsigned short* __restrict__ P4s16,
    const float* __restrict__ SQVb, const float* __restrict__ Cg,
    const float* __restrict__ QVR, const float* __restrict__ cbp,
    const float* __restrict__ PROBC, const float* __restrict__ PW,
    const float* __restrict__ PR, const float* __restrict__ Hmix,
    const float* __restrict__ W_hh, const float* __restrict__ b_hh,
    const float* __restrict__ cgx, const float* __restrict__ uh,
    const float* __restrict__ W_pred, const float* __restrict__ heads_map,
    const float* __restrict__ dwv, float* __restrict__ out) {
  int b = blockIdx.x;
  int tid = threadIdx.x;
  int lane = tid & 63, wv = tid >> 6;
  int cg3 = lane * 3;
  float hreg[16][3], wreg[8][3];
#pragma unroll
  for (int ii = 0; ii < 16; ++ii)
#pragma unroll
    for (int cc = 0; cc < 3; ++cc) hreg[ii][cc] = Hmix[(wv * 16 + ii) * 192 + cg3 + cc];
#pragma unroll
  for (int ii = 0; ii < 8; ++ii)
#pragma unroll
    for (int cc = 0; cc < 3; ++cc) wreg[ii][cc] = W_hh[(wv * 8 + ii) * 192 + cg3 + cc];
  float wph_reg[8], uh_reg[16];
  if (lane == 0) {
#pragma unroll
    for (int j = 0; j < 8; ++j) wph_reg[j] = W_pred[512 + wv * 8 + j];
#pragma unroll
    for (int ii = 0; ii < 16; ++ii) uh_reg[ii] = uh[wv * 16 + ii];
  }
  float bhh_reg = 0.f;
  if (tid >= 64 && tid < 256) bhh_reg = b_hh[tid - 64];
  float cgx0 = 0.f, cgx1 = 0.f, cgx2 = 0.f;
  if (tid < 64) { cgx0 = cgx[tid]; cgx1 = cgx[64 + tid]; cgx2 = cgx[128 + tid]; }
  float hmr = 0.f;
  if (tid >= 448 && tid < 452) hmr = heads_map[tid - 448];

  __shared__ float h_hist[128][64];
  __shared__ __align__(16) float PWl[128];
  __shared__ __align__(16) float PRl[128];
  __shared__ __align__(16) float h_cur[64];
  __shared__ float part_sc[8][40];
  __shared__ __align__(16) float e_l[40];
  __shared__ __align__(16) float inv_l[4];
  __shared__ __align__(16) float hisA[128];
  __shared__ float red8[8][128];
  __shared__ float redWg[8][192];
  __shared__ float redWh[8][192];
  __shared__ float gh_l[192];
  __shared__ float hwp_p[8], phis_p[8];
  __shared__ int resp_l[128];

  for (int i = tid; i < 128 * 64; i += 512) ((float*)h_hist)[i] = 0.f;
  if (tid < 64) h_cur[tid] = 0.f;
  if (tid >= 256 && tid < 384) resp_l[tid - 256] = response[(tid - 256) * 64 + b];
  float dw0 = dwv[0], dw1 = dwv[1];

  int sc_off = 0;
  if (lane < 40) { int hh = lane / 10, s = lane - hh * 10; sc_off = s * 256 + hh * 64 + wv * 8; }
  short8 pf8 = {};
  if (lane < 40) pf8 = *(const short8*)&P4s16[(size_t)b * 2560 + sc_off];
  float pf_sqv = 0.f;
  if (tid >= 384 && tid < 424) pf_sqv = SQVb[b * 40 + (tid - 384)];
  float pf_cg0[10], pf_cg1[10], pf_cg2[10];
  float pf_gxA0 = 0.f, pf_gxA1 = 0.f, pf_gxA2 = 0.f, pf_gxB0 = 0.f, pf_gxB1 = 0.f, pf_gxB2 = 0.f;
  if (tid < 64) {
#pragma unroll
    for (int s = 0; s < 10; ++s) {
      size_t base = (size_t)(b * 10 + s) * 192;
      pf_cg0[s] = Cg[base + tid]; pf_cg1[s] = Cg[base + 64 + tid]; pf_cg2[s] = Cg[base + 128 + tid];
    }
    size_t gb = (size_t)b * 1408 + 256;
    pf_gxA0 = QVR[gb + tid]; pf_gxA1 = QVR[gb + 64 + tid]; pf_gxA2 = QVR[gb + 128 + tid];
    pf_gxB0 = QVR[gb + 192 + tid]; pf_gxB1 = QVR[gb + 256 + tid]; pf_gxB2 = QVR[gb + 320 + tid];
  }
  float pf_cbp[10]; float pf_probc = 0.f;
  if (tid == 448) {
#pragma unroll
    for (int s = 0; s < 10; ++s) pf_cbp[s] = cbp[b * 10 + s];
    pf_probc = PROBC[b];
  }
  float4 pf_pw = make_float4(0, 0, 0, 0), pf_pr = pf_pw;
  if (tid >= 128 && tid < 160) pf_pw = *(const float4*)&PW[((size_t)(b * 128 + 0)) * 128 + 4 * (tid - 128)];
  else if (tid >= 160 && tid < 192) pf_pr = *(const float4*)&PR[((size_t)(b * 128 + 0)) * 128 + 4 * (tid - 160)];
  if (tid >= 128 && tid < 160) *(float4*)&PWl[4 * (tid - 128)] = pf_pw;
  else if (tid >= 160 && tid < 192) *(float4*)&PRl[4 * (tid - 160)] = pf_pr;
  if (tid >= 128 && tid < 160) pf_pw = *(const float4*)&PW[((size_t)(b * 128 + 1)) * 128 + 4 * (tid - 128)];
  else if (tid >= 160 && tid < 192) pf_pr = *(const float4*)&PR[((size_t)(b * 128 + 1)) * 128 + 4 * (tid - 160)];
  ldsbar();

  for (int t = 0; t < 128; ++t) {
    int tn = (t < 127) ? t + 1 : 127;
    int tbn = tn * 64 + b;
    // ===== phase A =====
    float4 ha = *(const float4*)&h_cur[wv * 8];
    float4 hb = *(const float4*)&h_cur[wv * 8 + 4];
    if (lane < 40) {
      const unsigned short* pp = (const unsigned short*)&pf8;
      float v = ha.x * bf2f(pp[0]) + ha.y * bf2f(pp[1]) + ha.z * bf2f(pp[2]) + ha.w * bf2f(pp[3])
              + hb.x * bf2f(pp[4]) + hb.y * bf2f(pp[5]) + hb.z * bf2f(pp[6]) + hb.w * bf2f(pp[7]);
      part_sc[wv][lane] = v;
      pf8 = *(const short8*)&P4s16[(size_t)tbn * 2560 + sc_off];
    }
    {
      float hl[8] = {ha.x, ha.y, ha.z, ha.w, hb.x, hb.y, hb.z, hb.w};
      float l0 = 0.f, l1 = 0.f, l2 = 0.f;
#pragma unroll
      for (int ii = 0; ii < 8; ++ii) {
        l0 += hl[ii] * wreg[ii][0]; l1 += hl[ii] * wreg[ii][1]; l2 += hl[ii] * wreg[ii][2];
      }
      redWg[wv][cg3] = l0; redWg[wv][cg3 + 1] = l1; redWg[wv][cg3 + 2] = l2;
      if (lane == 0) {
        float hp = 0.f;
#pragma unroll
        for (int j = 0; j < 8; ++j) hp += hl[j] * wph_reg[j];
        hwp_p[wv] = hp;
      }
    }
    {
      int j0 = wv * 16;
      float aR = 0.f, aA = 0.f;
#pragma unroll
      for (int k = 0; k < 16; ++k) {
        float hv = h_hist[j0 + k][lane];
        aA += PWl[j0 + k] * hv; aR += PRl[j0 + k] * hv;
      }
      red8[wv][lane] = aR; red8[wv][64 + lane] = aA;
    }
    ldsbar();
    // ===== phase B =====
    if (tid < 64) {
      float sR = 0.f, sA = 0.f;
#pragma unroll
      for (int g = 0; g < 8; ++g) { sR += red8[g][tid]; sA += red8[g][64 + tid]; }
      hisA[tid] = sR; hisA[64 + tid] = sA - sR;
    } else if (tid < 256) {
      int c = tid - 64; float g = 0.f;
#pragma unroll
      for (int gg = 0; gg < 8; ++gg) g += redWg[gg][c];
      gh_l[c] = g + bhh_reg;
    } else if (tid >= 384 && tid < 424) {
      int p = tid - 384;
      float s = pf_sqv;
#pragma unroll
      for (int w = 0; w < 8; ++w) s += part_sc[w][p];
      e_l[p] = __expf(s);
      pf_sqv = SQVb[tbn * 40 + p];
    }
    ldsbar();
    // ===== phase C =====
    {
      float4 h0 = *(const float4*)&hisA[wv * 16];
      float4 h1 = *(const float4*)&hisA[wv * 16 + 4];
      float4 h2 = *(const float4*)&hisA[wv * 16 + 8];
      float4 h3 = *(const float4*)&hisA[wv * 16 + 12];
      float hA[16] = {h0.x, h0.y, h0.z, h0.w, h1.x, h1.y, h1.z, h1.w,
                      h2.x, h2.y, h2.z, h2.w, h3.x, h3.y, h3.z, h3.w};
      float l0 = 0.f, l1 = 0.f, l2 = 0.f;
#pragma unroll
      for (int ii = 0; ii < 16; ++ii) {
        l0 += hA[ii] * hreg[ii][0]; l1 += hA[ii] * hreg[ii][1]; l2 += hA[ii] * hreg[ii][2];
      }
      redWh[wv][cg3] = l0; redWh[wv][cg3 + 1] = l1; redWh[wv][cg3 + 2] = l2;
      if (lane == 0) {
        float pp = 0.f;
#pragma unroll
        for (int ii = 0; ii < 16; ++ii) pp += hA[ii] * uh_reg[ii];
        phis_p[wv] = pp;
      }
    }
    if (tid >= 448 && tid < 452) {
      int h = tid - 448;
      float den = 0.f;
#pragma unroll
      for (int s = 0; s < 10; ++s) den += e_l[h * 10 + s];
      inv_l[h] = hmr / den;
    }
    ldsbar();
    // ===== phase D =====
    if (tid < 64 || tid == 448) {
      float4 iv = *(const float4*)&inv_l[0];
      float ev[40];
#pragma unroll
      for (int qq = 0; qq < 10; ++qq) *(float4*)&ev[4 * qq] = *(const float4*)&e_l[4 * qq];
      float ws[10];
#pragma unroll
      for (int s = 0; s < 10; ++s)
        ws[s] = iv.x * ev[s] + iv.y * ev[10 + s] + iv.z * ev[20 + s] + iv.w * ev[30 + s];
      if (tid < 64) {
        float gxh0 = 0.f, gxh1 = 0.f, gxh2 = 0.f;
#pragma unroll
        for (int g = 0; g < 8; ++g) {
          gxh0 += redWh[g][tid]; gxh1 += redWh[g][64 + tid]; gxh2 += redWh[g][128 + tid];
        }
        float gbg0 = 0.f, gbg1 = 0.f, gbg2 = 0.f;
#pragma unroll
        for (int s = 0; s < 10; ++s) {
          gbg0 += ws[s] * pf_cg0[s]; gbg1 += ws[s] * pf_cg1[s]; gbg2 += ws[s] * pf_cg2[s];
        }
        int rn = resp_l[t];
        float xr = dw0 * gbg0 + dw1 * gxh0 + (rn ? pf_gxA0 : pf_gxB0) + cgx0;
        float xz = dw0 * gbg1 + dw1 * gxh1 + (rn ? pf_gxA1 : pf_gxB1) + cgx1;
        float xn = dw0 * gbg2 + dw1 * gxh2 + (rn ? pf_gxA2 : pf_gxB2) + cgx2;
        float hr = gh_l[tid], hz = gh_l[64 + tid], hn = gh_l[128 + tid];
        float r = 1.f / (1.f + __expf(-(xr + hr)));
        float z = 1.f / (1.f + __expf(-(xz + hz)));
        float n = tanhf(xn + r * hn);
        float hnew = (1.f - z) * n + z * h_cur[tid];
        h_cur[tid] = hnew;
        if (t < 127) h_hist[t + 1][tid] = hnew;
#pragma unroll
        for (int s = 0; s < 10; ++s) {
          size_t base = (size_t)(tbn * 10 + s) * 192;
          pf_cg0[s] = Cg[base + tid]; pf_cg1[s] = Cg[base + 64 + tid]; pf_cg2[s] = Cg[base + 128 + tid];
        }
        size_t gb = (size_t)tbn * 1408 + 256;
        pf_gxA0 = QVR[gb + tid]; pf_gxA1 = QVR[gb + 64 + tid]; pf_gxA2 = QVR[gb + 128 + tid];
        pf_gxB0 = QVR[gb + 192 + tid]; pf_gxB1 = QVR[gb + 256 + tid]; pf_gxB2 = QVR[gb + 320 + tid];
      } else {
        float pbg = 0.f;
#pragma unroll
        for (int s = 0; s < 10; ++s) pbg += ws[s] * pf_cbp[s];
        float ph = 0.f, hw = 0.f;
#pragma unroll
        for (int g = 0; g < 8; ++g) { ph += phis_p[g]; hw += hwp_p[g]; }
        out[b * 128 + t] = dw0 * pbg + dw1 * ph + hw + pf_probc;
#pragma unroll
        for (int s = 0; s < 10; ++s) pf_cbp[s] = cbp[tbn * 10 + s];
        pf_probc = PROBC[tbn];
      }
    } else if (tid >= 128 && tid < 192) {
      if (tid < 160) *(float4*)&PWl[4 * (tid - 128)] = pf_pw;
      else *(float4*)&PRl[4 * (tid - 160)] = pf_pr;
      int rn2 = (t + 2 < 128) ? t + 2 : 127;
      if (tid < 160) pf_pw = *(const float4*)&PW[((size_t)(b * 128 + rn2)) * 128 + 4 * (tid - 128)];
      else pf_pr = *(const float4*)&PR[((size_t)(b * 128 + rn2)) * 128 + 4 * (tid - 160)];
    }
    ldsbar();
  }
}

// ---------------- launch ----------------
extern "C" void kernel_launch(void* const* d_in, const int* in_sizes, int n_in,
                              void* d_out, int out_size, void* d_ws, size_t ws_size,
                              hipStream_t stream) {
  const int* prob_id      = (const int*)d_in[0];
  const int* skills       = (const int*)d_in[1];
  const int* response     = (const int*)d_in[2];
  const int* bg_index     = (const int*)d_in[3];
  const int* mem_prob_ids = (const int*)d_in[4];
  const int* mem_resp     = (const int*)d_in[5];
  const int* mem_concepts = (const int*)d_in[6];
  const float* states_mem  = (const float*)d_in[7];
  const float* concept_emb = (const float*)d_in[8];
  const float* prob_emb    = (const float*)d_in[9];
  const float* W_pred   = (const float*)d_in[10];
  const float* b_pred   = (const float*)d_in[11];
  const float* W_ih     = (const float*)d_in[12];
  const float* W_hh     = (const float*)d_in[13];
  const float* b_ih     = (const float*)d_in[14];
  const float* b_hh     = (const float*)d_in[15];
  const float* W_batch  = (const float*)d_in[16];
  const float* b_batch  = (const float*)d_in[17];
  const float* W_bg     = (const float*)d_in[18];
  const float* b_bg     = (const float*)d_in[19];
  const float* W_bgint  = (const float*)d_in[20];
  const float* b_bgint  = (const float*)d_in[21];
  const float* W_hisint = (const float*)d_in[22];
  const float* b_hisint = (const float*)d_in[23];
  const float* W_inmap  = (const float*)d_in[24];
  const float* b_inmap  = (const float*)d_in[25];
  const float* dir_w    = (const float*)d_in[26];
  const float* heads_map= (const float*)d_in[27];
  float* out = (float*)d_out;

  float* w = (float*)d_ws;
  size_t off = 0;
  auto alloc = [&](size_t n) { float* p = w + off; off += (n + 3) & ~(size_t)3; return p; };
  float* M12    = alloc(640 * 192);
  unsigned short* B1T = (unsigned short*)alloc(640 * 192 / 2);
  float* Hmix   = alloc(128 * 192);
  unsigned short* BRQT = (unsigned short*)alloc(1408 * 128 / 2);
  float* bias_all = alloc(1408);
  float* c4     = alloc(256);
  float* cgx    = alloc(192);
  float* uh     = alloc(128);
  float* bgp    = alloc(384);
  float* c0     = alloc(1);
  float* dwv    = alloc(2);
  float* V      = alloc((size_t)8192 * 128);
  unsigned short* V16 = (unsigned short*)alloc((size_t)8192 * 128 / 2);
  float* VT     = alloc((size_t)64 * 128 * 128);
  float* QVR    = alloc((size_t)8192 * 1408);
  float* S      = alloc((size_t)64 * 128 * 128);   // becomes PW in-place
  float* PR     = alloc((size_t)64 * 128 * 128);
  unsigned short* AHV = (unsigned short*)alloc((size_t)NITEM * 192 / 2);
  unsigned short* P4s16 = (unsigned short*)alloc((size_t)NITEM * 256 / 2);
  float* Cg     = alloc((size_t)NITEM * 192);
  float* SQVb   = alloc((size_t)8192 * 40);
  float* cbp    = alloc((size_t)NITEM);
  float* PROBC  = alloc(8192);
  (void)ws_size; (void)in_sizes; (void)n_in; (void)out_size;

  build_v<<<8192, 64, 0, stream>>>(prob_id, skills, concept_emb, prob_emb, V, VT, V16);
  gemm_f32<<<dim3(3, 10, 1), 256, 0, stream>>>(W_inmap, W_ih, M12, nullptr,
      640, 192, 256, 256, 192, 192, 0, 0, 0, 1.0f);
  k_small<<<1290, 256, 0, stream>>>(W_batch, W_bg, b_bg, W_bgint, b_bgint, W_hisint, b_hisint,
      W_ih, b_ih, b_inmap, W_pred, b_pred, dir_w, b_batch, M12, B1T, Hmix, BRQT, bias_all,
      c4, cgx, uh, bgp, c0, dwv);
  gather_ahv<<<NITEM * 96 / 256, 256, 0, stream>>>(bg_index, mem_prob_ids, mem_concepts,
      states_mem, concept_emb, prob_emb, AHV);
  mfma_qvr<<<dim3(64, 11), 256, 0, stream>>>(V16, BRQT, bias_all, QVR);
  gemm_f32<<<dim3(2, 2, 64), 256, 0, stream>>>(V, VT, S, nullptr,
      128, 128, 128, 8192, 128, 128, 128, 16384, 16384, 0.08838834764831845f);
  prep_pw<<<8192, 64, 0, stream>>>(S, response, S, PR);
  big_gemm<<<dim3(640), 256, 0, stream>>>(bg_index, mem_resp, AHV, B1T, c4, P4s16, Cg);
  k5<<<8192, 256, 0, stream>>>(bg_index, mem_resp, AHV, QVR, b_bg, bgp, V, W_pred, c0,
      SQVb, cbp, PROBC);
  seq_kernel<<<64, 512, 0, stream>>>(response, P4s16, SQVb, Cg, QVR, cbp, PROBC,
      S, PR, Hmix, W_hh, b_hh, cgx, uh, W_pred, heads_map, dwv, out);
}